// Round 7
// baseline (147.790 us; speedup 1.0000x reference)
//
#include <hip/hip_runtime.h>

#define N_NODES 50000
#define N_EDGES 500000
#define IN_C 128
#define HID_C 128
#define OUT_C 64

#define SCAN_NB ((N_NODES + 255) / 256)  // 196 blocks
#define NGROUPS (N_NODES / 16)           // 3125 node-groups of 16

typedef short s16x8 __attribute__((ext_vector_type(8)));
typedef float f32x4 __attribute__((ext_vector_type(4)));

__device__ __forceinline__ unsigned short f2bf(float f) {
    unsigned int u = __float_as_uint(f);
    u = (u + 0x7FFF + ((u >> 16) & 1)) >> 16;  // round-to-nearest-even
    return (unsigned short)u;
}
__device__ __forceinline__ float bf2f(unsigned short u) {
    return __uint_as_float(((unsigned int)u) << 16);
}

// ---------------- zero ----------------

__global__ __launch_bounds__(256) void zero_kernel(int4* __restrict__ p, int n4) {
    int i = blockIdx.x * blockDim.x + threadIdx.x;
    if (i < n4) p[i] = make_int4(0, 0, 0, 0);
}

// ---------------- CSR build ----------------

__global__ void deg_kernel(const int* __restrict__ dst, int* __restrict__ degi) {
    int e = blockIdx.x * blockDim.x + threadIdx.x;
    if (e < N_EDGES) atomicAdd(&degi[dst[e]], 1);
}

__global__ __launch_bounds__(256) void scan1_kernel(const int* __restrict__ degi,
                                                    int* __restrict__ rowptr,
                                                    int* __restrict__ blocksum,
                                                    float* __restrict__ dinv) {
    __shared__ int sh[256];
    const int t = threadIdx.x;
    const int i = blockIdx.x * 256 + t;
    int v = (i < N_NODES) ? degi[i] : 0;
    sh[t] = v;
    __syncthreads();
#pragma unroll
    for (int off = 1; off < 256; off <<= 1) {
        int tmp = (t >= off) ? sh[t - off] : 0;
        __syncthreads();
        sh[t] += tmp;
        __syncthreads();
    }
    if (i < N_NODES) {
        rowptr[i] = sh[t];
        dinv[i] = rsqrtf((float)v + 1.0f);
    }
    if (t == 255) blocksum[blockIdx.x] = sh[255];
}

__global__ __launch_bounds__(256) void scan2_kernel(int* __restrict__ blocksum) {
    __shared__ int sh[256];
    const int t = threadIdx.x;
    int v = (t < SCAN_NB) ? blocksum[t] : 0;
    sh[t] = v;
    __syncthreads();
#pragma unroll
    for (int off = 1; off < 256; off <<= 1) {
        int tmp = (t >= off) ? sh[t - off] : 0;
        __syncthreads();
        sh[t] += tmp;
        __syncthreads();
    }
    if (t < SCAN_NB) blocksum[t] = sh[t] - v;
}

__global__ __launch_bounds__(256) void scan3_kernel(int* __restrict__ rowptr,
                                                    int* __restrict__ degi,
                                                    const int* __restrict__ blocksum) {
    const int i = blockIdx.x * 256 + threadIdx.x;
    if (i < N_NODES) {
        int d = degi[i];
        int ex = rowptr[i] - d + blocksum[blockIdx.x];
        rowptr[i] = ex;
        degi[i] = ex;  // cursor for fill
    }
    if (i == 0) rowptr[N_NODES] = N_EDGES;
}

__global__ void fill_kernel(const int* __restrict__ src, const int* __restrict__ dst,
                            int* __restrict__ cursor, int* __restrict__ csr_src) {
    int e = blockIdx.x * blockDim.x + threadIdx.x;
    if (e < N_EDGES) {
        int d = dst[e];
        int pos = atomicAdd(&cursor[d], 1);
        csr_src[pos] = src[e];
    }
}

// ---------------- MFMA GEMM: H(chunked bf16) = dinv[n] * (X[n,128] @ W[128,NOUT]) ----------------
// H layout: [NOUT/32][N_NODES][32] bf16 (channel chunks of 32 = 64B rows, L2-resident per chunk).
// XBF16 input (layer 2) is itself chunked [.][N][32]; fp32 input (layer 1) is row-major.

template <int NOUT, bool XBF16>
__global__ __launch_bounds__(256) void mfma_gemm(const void* __restrict__ Xv,
                                                 const float* __restrict__ W,
                                                 const float* __restrict__ dinv,
                                                 unsigned short* __restrict__ H, int nrows) {
    constexpr int NT = NOUT / 64;       // n-tiles per wave (2 for 128, 1 for 64)
    constexpr int SP = 136;             // padded LDS row stride (shorts)
    __shared__ unsigned short Xl[64 * SP];

    const int tid = threadIdx.x;
    const int w = tid >> 6;
    const int lane = tid & 63;
    const int kk = lane >> 4;           // 0..3
    const int cl = lane & 15;
    const int row0 = blockIdx.x * 64;

    for (int c = tid; c < 64 * 32; c += 256) {
        int r = c >> 5, cc = c & 31;    // cc: ushort4 index within the 128-ch row
        int gr = row0 + r;
        ushort4 o;
        if (XBF16) {
            if (gr < nrows) {
                int ckk = cc >> 3;      // input chunk (32 ch = 8 ushort4)
                o = ((const ushort4*)Xv)[((size_t)ckk * N_NODES + gr) * 8 + (cc & 7)];
            } else {
                o = make_ushort4(0, 0, 0, 0);
            }
        } else {
            if (gr < nrows) {
                float4 v = ((const float4*)Xv)[(size_t)gr * 32 + cc];
                o = make_ushort4(f2bf(v.x), f2bf(v.y), f2bf(v.z), f2bf(v.w));
            } else {
                o = make_ushort4(0, 0, 0, 0);
            }
        }
        *(ushort4*)&Xl[r * SP + cc * 4] = o;
    }

    s16x8 bfrag[NT][4];
#pragma unroll
    for (int i = 0; i < NT; i++) {
        int colg = (w * NT + i) * 16 + cl;
#pragma unroll
        for (int s = 0; s < 4; s++) {
#pragma unroll
            for (int j = 0; j < 8; j++) {
                int k = s * 32 + kk * 8 + j;
                bfrag[i][s][j] = (short)f2bf(W[k * NOUT + colg]);
            }
        }
    }

    __syncthreads();

    f32x4 acc[4][NT];
#pragma unroll
    for (int rt = 0; rt < 4; rt++)
#pragma unroll
        for (int i = 0; i < NT; i++) acc[rt][i] = (f32x4){0.f, 0.f, 0.f, 0.f};

#pragma unroll
    for (int rt = 0; rt < 4; rt++) {
        const int rl = rt * 16 + cl;
        s16x8 a[4];
#pragma unroll
        for (int s = 0; s < 4; s++)
            a[s] = *(const s16x8*)&Xl[rl * SP + s * 32 + kk * 8];
#pragma unroll
        for (int i = 0; i < NT; i++)
#pragma unroll
            for (int s = 0; s < 4; s++)
                acc[rt][i] = __builtin_amdgcn_mfma_f32_16x16x32_bf16(a[s], bfrag[i][s],
                                                                     acc[rt][i], 0, 0, 0);
    }

#pragma unroll
    for (int rt = 0; rt < 4; rt++) {
        float4 dv = *(const float4*)&dinv[row0 + rt * 16 + kk * 4];
        float dvv[4] = {dv.x, dv.y, dv.z, dv.w};
#pragma unroll
        for (int i = 0; i < NT; i++) {
            int colg = (w * NT + i) * 16 + cl;
            int ckk = colg >> 5;
            int cw = colg & 31;
#pragma unroll
            for (int r = 0; r < 4; r++) {
                int rowg = row0 + rt * 16 + kk * 4 + r;
                if (rowg < nrows)
                    H[((size_t)ckk * N_NODES + rowg) * 32 + cw] = f2bf(dvv[r] * acc[rt][i][r]);
            }
        }
    }
}

// ---------------- chunked fused aggregation + epilogue ----------------
// H chunked [NCHUNKS][N][32] bf16. Each block handles ONE chunk x 16 nodes (16 lanes/node).
// Blocks are XCD-pinned: chunk = (blockIdx.x & 7) / XPC, so each chunk's 3.2MB table
// stays resident in the L2s of its dedicated XCD set (round-robin dispatch heuristic;
// neutral if mapping differs). out[n][c] = (relu?)(dinv[n]*(H'[n][c]+sum_s H'[s][c])+b[c])

template <int NCHUNKS, bool RELU, bool OUTF32>
__global__ __launch_bounds__(256) void agg_kernel(const int* __restrict__ rowptr,
                                                  const int* __restrict__ csr_src,
                                                  const float* __restrict__ dinv,
                                                  const unsigned int* __restrict__ H,  // bf16x2
                                                  const float* __restrict__ b,
                                                  void* __restrict__ outv) {
    constexpr int XPC = 8 / NCHUNKS;  // XCDs per chunk
    const int xx = blockIdx.x & 7;
    const int ck = xx / XPC;
    const int group = (blockIdx.x >> 3) * XPC + (xx % XPC);
    if (group >= NGROUPS) return;
    const int node = group * 16 + (threadIdx.x >> 4);
    const int c2 = threadIdx.x & 15;  // bf16x2 lane within 32-ch chunk

    const unsigned int* __restrict__ Hc = H + (size_t)ck * N_NODES * 16;

    float acc0, acc1;
    {
        unsigned int hv = Hc[(size_t)node * 16 + c2];
        acc0 = bf2f((unsigned short)(hv & 0xffff));
        acc1 = bf2f((unsigned short)(hv >> 16));
    }

    int e = rowptr[node];
    const int end = rowptr[node + 1];

    for (; e + 3 < end; e += 4) {
        int s0 = csr_src[e];
        int s1 = csr_src[e + 1];
        int s2 = csr_src[e + 2];
        int s3 = csr_src[e + 3];
        unsigned int h0 = Hc[(size_t)s0 * 16 + c2];
        unsigned int h1 = Hc[(size_t)s1 * 16 + c2];
        unsigned int h2 = Hc[(size_t)s2 * 16 + c2];
        unsigned int h3 = Hc[(size_t)s3 * 16 + c2];
        acc0 += bf2f((unsigned short)(h0 & 0xffff));
        acc1 += bf2f((unsigned short)(h0 >> 16));
        acc0 += bf2f((unsigned short)(h1 & 0xffff));
        acc1 += bf2f((unsigned short)(h1 >> 16));
        acc0 += bf2f((unsigned short)(h2 & 0xffff));
        acc1 += bf2f((unsigned short)(h2 >> 16));
        acc0 += bf2f((unsigned short)(h3 & 0xffff));
        acc1 += bf2f((unsigned short)(h3 >> 16));
    }
    for (; e < end; e++) {
        int s0 = csr_src[e];
        unsigned int h0 = Hc[(size_t)s0 * 16 + c2];
        acc0 += bf2f((unsigned short)(h0 & 0xffff));
        acc1 += bf2f((unsigned short)(h0 >> 16));
    }

    const float dn = dinv[node];
    const int cbase = ck * 32 + 2 * c2;
    acc0 = fmaf(dn, acc0, b[cbase]);
    acc1 = fmaf(dn, acc1, b[cbase + 1]);

    if (RELU) {
        acc0 = fmaxf(acc0, 0.f);
        acc1 = fmaxf(acc1, 0.f);
    }
    if (OUTF32) {
        // row-major fp32 output [N][NCHUNKS*32]
        float2* out = (float2*)outv;
        out[(size_t)node * (NCHUNKS * 16) + ck * 16 + c2] = make_float2(acc0, acc1);
    } else {
        // chunked bf16 output [NCHUNKS][N][32]
        unsigned int* out = (unsigned int*)outv;
        out[((size_t)ck * N_NODES + node) * 16 + c2] =
            (unsigned int)f2bf(acc0) | ((unsigned int)f2bf(acc1) << 16);
    }
}

// ---------------- launch ----------------

extern "C" void kernel_launch(void* const* d_in, const int* in_sizes, int n_in,
                              void* d_out, int out_size, void* d_ws, size_t ws_size,
                              hipStream_t stream) {
    const float* x  = (const float*)d_in[0];
    const int*   ei = (const int*)d_in[1];
    const float* W1 = (const float*)d_in[2];
    const float* b1 = (const float*)d_in[3];
    const float* W2 = (const float*)d_in[4];
    const float* b2 = (const float*)d_in[5];

    const int* src = ei;
    const int* dst = ei + N_EDGES;

    // workspace layout
    unsigned short* h1 = (unsigned short*)d_ws;                 // [4][N][32] bf16 (pre-scaled)
    unsigned short* h2 = h1 + (size_t)N_NODES * HID_C;          // [4][N][32] bf16 (activations)
    float* dinv  = (float*)(h2 + (size_t)N_NODES * HID_C);      // 50,048 f
    int*   degi  = (int*)(dinv + 50048);                        // 50,048 i (cursor)
    int*   rowptr = degi + 50048;                               // 50,001 i
    int*   csr   = rowptr + 50051;                              // 500,000 i
    int*   bsum  = csr + 500000;                                // 256 i
    unsigned short* h3 = h1;                                    // reuse h1: [2][N][32] bf16

    // --- CSR build ---
    {
        int n4 = (N_NODES + 3) / 4;
        zero_kernel<<<(n4 + 255) / 256, 256, 0, stream>>>((int4*)degi, n4);
    }
    deg_kernel<<<(N_EDGES + 255) / 256, 256, 0, stream>>>(dst, degi);
    scan1_kernel<<<SCAN_NB, 256, 0, stream>>>(degi, rowptr, bsum, dinv);
    scan2_kernel<<<1, 256, 0, stream>>>(bsum);
    scan3_kernel<<<SCAN_NB, 256, 0, stream>>>(rowptr, degi, bsum);
    fill_kernel<<<(N_EDGES + 255) / 256, 256, 0, stream>>>(src, dst, degi, csr);

    const int gemm_grid = (N_NODES + 63) / 64;

    // --- layer 1 ---  (h1: 4 chunks, 2 XCDs each)
    mfma_gemm<HID_C, false><<<gemm_grid, 256, 0, stream>>>(x, W1, dinv, h1, N_NODES);
    {
        const int grid = 8 * ((NGROUPS + 1) / 2);  // XPC=2
        agg_kernel<4, true, false><<<grid, 256, 0, stream>>>(
            rowptr, csr, dinv, (const unsigned int*)h1, b1, h2);
    }

    // --- layer 2 ---  (h3: 2 chunks, 4 XCDs each)
    mfma_gemm<OUT_C, true><<<gemm_grid, 256, 0, stream>>>(h2, W2, dinv, h3, N_NODES);
    {
        const int grid = 8 * ((NGROUPS + 3) / 4);  // XPC=4
        agg_kernel<2, false, true><<<grid, 256, 0, stream>>>(
            rowptr, csr, dinv, (const unsigned int*)h3, b2, d_out);
    }
}

// Round 8
// 140.306 us; speedup vs baseline: 1.0533x; 1.0533x over previous
//
#include <hip/hip_runtime.h>

#define N_NODES 50000
#define N_EDGES 500000
#define IN_C 128
#define HID_C 128
#define OUT_C 64

#define SCAN_NB ((N_NODES + 255) / 256)  // 196 blocks

typedef short s16x8 __attribute__((ext_vector_type(8)));
typedef float f32x4 __attribute__((ext_vector_type(4)));

__device__ __forceinline__ unsigned short f2bf(float f) {
    unsigned int u = __float_as_uint(f);
    u = (u + 0x7FFF + ((u >> 16) & 1)) >> 16;  // round-to-nearest-even
    return (unsigned short)u;
}
__device__ __forceinline__ float bf2f(unsigned short u) {
    return __uint_as_float(((unsigned int)u) << 16);
}

// ---------------- zero ----------------

__global__ __launch_bounds__(256) void zero_kernel(int4* __restrict__ p, int n4) {
    int i = blockIdx.x * blockDim.x + threadIdx.x;
    if (i < n4) p[i] = make_int4(0, 0, 0, 0);
}

// ---------------- CSR build ----------------

__global__ void deg_kernel(const int* __restrict__ dst, int* __restrict__ degi) {
    int e = blockIdx.x * blockDim.x + threadIdx.x;
    if (e < N_EDGES) atomicAdd(&degi[dst[e]], 1);
}

// scan1: per-block inclusive prefix of degi -> rowptr (in place), block sums, dinv
__global__ __launch_bounds__(256) void scan1_kernel(const int* __restrict__ degi,
                                                    int* __restrict__ rowptr,
                                                    int* __restrict__ blocksum,
                                                    float* __restrict__ dinv) {
    __shared__ int sh[256];
    const int t = threadIdx.x;
    const int i = blockIdx.x * 256 + t;
    int v = (i < N_NODES) ? degi[i] : 0;
    sh[t] = v;
    __syncthreads();
#pragma unroll
    for (int off = 1; off < 256; off <<= 1) {
        int tmp = (t >= off) ? sh[t - off] : 0;
        __syncthreads();
        sh[t] += tmp;
        __syncthreads();
    }
    if (i < N_NODES) {
        rowptr[i] = sh[t];
        dinv[i] = rsqrtf((float)v + 1.0f);
    }
    if (t == 255) blocksum[blockIdx.x] = sh[255];
}

// scan23: every block redundantly scans the 196 block sums in LDS (cheaper than a
// separate dispatch), then converts rowptr to global exclusive + writes cursor.
__global__ __launch_bounds__(256) void scan23_kernel(int* __restrict__ rowptr,
                                                     int* __restrict__ degi,
                                                     const int* __restrict__ blocksum) {
    __shared__ int sh[256];
    const int t = threadIdx.x;
    int v = (t < SCAN_NB) ? blocksum[t] : 0;
    sh[t] = v;
    __syncthreads();
#pragma unroll
    for (int off = 1; off < 256; off <<= 1) {
        int tmp = (t >= off) ? sh[t - off] : 0;
        __syncthreads();
        sh[t] += tmp;
        __syncthreads();
    }
    const int myoff = sh[blockIdx.x] - blocksum[blockIdx.x];  // exclusive prefix of my block
    const int i = blockIdx.x * 256 + t;
    if (i < N_NODES) {
        int d = degi[i];
        int ex = rowptr[i] - d + myoff;
        rowptr[i] = ex;
        degi[i] = ex;  // cursor for fill
    }
    if (i == 0) rowptr[N_NODES] = N_EDGES;
}

__global__ void fill_kernel(const int* __restrict__ src, const int* __restrict__ dst,
                            int* __restrict__ cursor, int* __restrict__ csr_src) {
    int e = blockIdx.x * blockDim.x + threadIdx.x;
    if (e < N_EDGES) {
        int d = dst[e];
        int pos = atomicAdd(&cursor[d], 1);
        csr_src[pos] = src[e];
    }
}

// ---------------- MFMA GEMM: H[n, NOUT](bf16) = dinv[n] * (X[n,128] @ W[128,NOUT]) ----------------

template <int NOUT, bool XBF16>
__global__ __launch_bounds__(256) void mfma_gemm(const void* __restrict__ Xv,
                                                 const float* __restrict__ W,
                                                 const float* __restrict__ dinv,
                                                 unsigned short* __restrict__ H, int nrows) {
    constexpr int NT = NOUT / 64;       // n-tiles per wave (2 for 128, 1 for 64)
    constexpr int SP = 136;             // padded LDS row stride (shorts)
    __shared__ unsigned short Xl[64 * SP];

    const int tid = threadIdx.x;
    const int w = tid >> 6;
    const int lane = tid & 63;
    const int kk = lane >> 4;           // 0..3
    const int cl = lane & 15;
    const int row0 = blockIdx.x * 64;

    for (int c = tid; c < 64 * 32; c += 256) {
        int r = c >> 5, cc = c & 31;
        int gr = row0 + r;
        ushort4 o;
        if (XBF16) {
            o = (gr < nrows) ? ((const ushort4*)Xv)[(size_t)gr * 32 + cc]
                             : make_ushort4(0, 0, 0, 0);
        } else {
            if (gr < nrows) {
                float4 v = ((const float4*)Xv)[(size_t)gr * 32 + cc];
                o = make_ushort4(f2bf(v.x), f2bf(v.y), f2bf(v.z), f2bf(v.w));
            } else {
                o = make_ushort4(0, 0, 0, 0);
            }
        }
        *(ushort4*)&Xl[r * SP + cc * 4] = o;
    }

    s16x8 bfrag[NT][4];
#pragma unroll
    for (int i = 0; i < NT; i++) {
        int colg = (w * NT + i) * 16 + cl;
#pragma unroll
        for (int s = 0; s < 4; s++) {
#pragma unroll
            for (int j = 0; j < 8; j++) {
                int k = s * 32 + kk * 8 + j;
                bfrag[i][s][j] = (short)f2bf(W[k * NOUT + colg]);
            }
        }
    }

    __syncthreads();

    f32x4 acc[4][NT];
#pragma unroll
    for (int rt = 0; rt < 4; rt++)
#pragma unroll
        for (int i = 0; i < NT; i++) acc[rt][i] = (f32x4){0.f, 0.f, 0.f, 0.f};

#pragma unroll
    for (int rt = 0; rt < 4; rt++) {
        const int rl = rt * 16 + cl;
        s16x8 a[4];
#pragma unroll
        for (int s = 0; s < 4; s++)
            a[s] = *(const s16x8*)&Xl[rl * SP + s * 32 + kk * 8];
#pragma unroll
        for (int i = 0; i < NT; i++)
#pragma unroll
            for (int s = 0; s < 4; s++)
                acc[rt][i] = __builtin_amdgcn_mfma_f32_16x16x32_bf16(a[s], bfrag[i][s],
                                                                     acc[rt][i], 0, 0, 0);
    }

#pragma unroll
    for (int rt = 0; rt < 4; rt++) {
        float4 dv = *(const float4*)&dinv[row0 + rt * 16 + kk * 4];
        float dvv[4] = {dv.x, dv.y, dv.z, dv.w};
#pragma unroll
        for (int i = 0; i < NT; i++) {
            int colg = (w * NT + i) * 16 + cl;
#pragma unroll
            for (int r = 0; r < 4; r++) {
                int rowg = row0 + rt * 16 + kk * 4 + r;
                if (rowg < nrows) H[(size_t)rowg * NOUT + colg] = f2bf(dvv[r] * acc[rt][i][r]);
            }
        }
    }
}

// ---------------- agg layer 1 (128 ch): 1 node per WAVE, half-wave edge split ----------------
// H' pre-scaled bf16 [N][128]. Lane: half=(tid>>5)&1, q=tid&31 -> channels 4q..4q+3 (uint2=8B).
// Each half processes alternate edge groups; fold with shfl_xor(32). Loop is wave-uniform.

__global__ __launch_bounds__(256) void agg128_kernel(const int* __restrict__ rowptr,
                                                     const int* __restrict__ csr,
                                                     const float* __restrict__ dinv,
                                                     const uint2* __restrict__ H,  // 32 per row
                                                     const float* __restrict__ b,
                                                     uint2* __restrict__ out) {
    const int node = blockIdx.x * 4 + (threadIdx.x >> 6);
    const int half = (threadIdx.x >> 5) & 1;
    const int q = threadIdx.x & 31;

    float a0 = 0.f, a1 = 0.f, a2 = 0.f, a3 = 0.f;
    const int e0 = rowptr[node];
    const int cnt = rowptr[node + 1] - e0;
    const int base = e0 + half * 4;

    int k = 0;
    for (; k + 8 <= cnt; k += 8) {  // 8 edges/iter, 4 per half
        int i0 = csr[base + k];
        int i1 = csr[base + k + 1];
        int i2 = csr[base + k + 2];
        int i3 = csr[base + k + 3];
        uint2 h0 = H[(size_t)i0 * 32 + q];
        uint2 h1 = H[(size_t)i1 * 32 + q];
        uint2 h2 = H[(size_t)i2 * 32 + q];
        uint2 h3 = H[(size_t)i3 * 32 + q];
        a0 += bf2f((unsigned short)(h0.x & 0xffff)) + bf2f((unsigned short)(h1.x & 0xffff)) +
              bf2f((unsigned short)(h2.x & 0xffff)) + bf2f((unsigned short)(h3.x & 0xffff));
        a1 += bf2f((unsigned short)(h0.x >> 16)) + bf2f((unsigned short)(h1.x >> 16)) +
              bf2f((unsigned short)(h2.x >> 16)) + bf2f((unsigned short)(h3.x >> 16));
        a2 += bf2f((unsigned short)(h0.y & 0xffff)) + bf2f((unsigned short)(h1.y & 0xffff)) +
              bf2f((unsigned short)(h2.y & 0xffff)) + bf2f((unsigned short)(h3.y & 0xffff));
        a3 += bf2f((unsigned short)(h0.y >> 16)) + bf2f((unsigned short)(h1.y >> 16)) +
              bf2f((unsigned short)(h2.y >> 16)) + bf2f((unsigned short)(h3.y >> 16));
    }
    for (int j = k + half; j < cnt; j += 2) {  // tail: 2 edges/iter (1 per half)
        int s = csr[e0 + j];
        uint2 h = H[(size_t)s * 32 + q];
        a0 += bf2f((unsigned short)(h.x & 0xffff));
        a1 += bf2f((unsigned short)(h.x >> 16));
        a2 += bf2f((unsigned short)(h.y & 0xffff));
        a3 += bf2f((unsigned short)(h.y >> 16));
    }

    a0 += __shfl_xor(a0, 32);
    a1 += __shfl_xor(a1, 32);
    a2 += __shfl_xor(a2, 32);
    a3 += __shfl_xor(a3, 32);

    if (half == 0) {
        const float dn = dinv[node];
        uint2 self = H[(size_t)node * 32 + q];
        float4 bb = *(const float4*)&b[q * 4];
        float r0 = fmaf(dn, bf2f((unsigned short)(self.x & 0xffff)) + a0, bb.x);
        float r1 = fmaf(dn, bf2f((unsigned short)(self.x >> 16)) + a1, bb.y);
        float r2 = fmaf(dn, bf2f((unsigned short)(self.y & 0xffff)) + a2, bb.z);
        float r3 = fmaf(dn, bf2f((unsigned short)(self.y >> 16)) + a3, bb.w);
        r0 = fmaxf(r0, 0.f);
        r1 = fmaxf(r1, 0.f);
        r2 = fmaxf(r2, 0.f);
        r3 = fmaxf(r3, 0.f);
        uint2 o;
        o.x = (unsigned int)f2bf(r0) | ((unsigned int)f2bf(r1) << 16);
        o.y = (unsigned int)f2bf(r2) | ((unsigned int)f2bf(r3) << 16);
        out[(size_t)node * 32 + q] = o;
    }
}

// ---------------- agg layer 2 (64 ch): 1 node per WAVE, half-wave edge split, fp32 out ----------------
// H' pre-scaled bf16 [N][64]. Lane: half, q=tid&31 -> channels 2q,2q+1 (uint=4B).

__global__ __launch_bounds__(256) void agg64_kernel(const int* __restrict__ rowptr,
                                                    const int* __restrict__ csr,
                                                    const float* __restrict__ dinv,
                                                    const unsigned int* __restrict__ H,  // 32/row
                                                    const float* __restrict__ b,
                                                    float2* __restrict__ out) {
    const int node = blockIdx.x * 4 + (threadIdx.x >> 6);
    const int half = (threadIdx.x >> 5) & 1;
    const int q = threadIdx.x & 31;

    float a0 = 0.f, a1 = 0.f;
    const int e0 = rowptr[node];
    const int cnt = rowptr[node + 1] - e0;
    const int base = e0 + half * 4;

    int k = 0;
    for (; k + 8 <= cnt; k += 8) {
        int i0 = csr[base + k];
        int i1 = csr[base + k + 1];
        int i2 = csr[base + k + 2];
        int i3 = csr[base + k + 3];
        unsigned int h0 = H[(size_t)i0 * 32 + q];
        unsigned int h1 = H[(size_t)i1 * 32 + q];
        unsigned int h2 = H[(size_t)i2 * 32 + q];
        unsigned int h3 = H[(size_t)i3 * 32 + q];
        a0 += bf2f((unsigned short)(h0 & 0xffff)) + bf2f((unsigned short)(h1 & 0xffff)) +
              bf2f((unsigned short)(h2 & 0xffff)) + bf2f((unsigned short)(h3 & 0xffff));
        a1 += bf2f((unsigned short)(h0 >> 16)) + bf2f((unsigned short)(h1 >> 16)) +
              bf2f((unsigned short)(h2 >> 16)) + bf2f((unsigned short)(h3 >> 16));
    }
    for (int j = k + half; j < cnt; j += 2) {
        int s = csr[e0 + j];
        unsigned int h = H[(size_t)s * 32 + q];
        a0 += bf2f((unsigned short)(h & 0xffff));
        a1 += bf2f((unsigned short)(h >> 16));
    }

    a0 += __shfl_xor(a0, 32);
    a1 += __shfl_xor(a1, 32);

    if (half == 0) {
        const float dn = dinv[node];
        unsigned int self = H[(size_t)node * 32 + q];
        float2 bb = *(const float2*)&b[q * 2];
        float r0 = fmaf(dn, bf2f((unsigned short)(self & 0xffff)) + a0, bb.x);
        float r1 = fmaf(dn, bf2f((unsigned short)(self >> 16)) + a1, bb.y);
        out[(size_t)node * 32 + q] = make_float2(r0, r1);
    }
}

// ---------------- launch ----------------

extern "C" void kernel_launch(void* const* d_in, const int* in_sizes, int n_in,
                              void* d_out, int out_size, void* d_ws, size_t ws_size,
                              hipStream_t stream) {
    const float* x  = (const float*)d_in[0];
    const int*   ei = (const int*)d_in[1];
    const float* W1 = (const float*)d_in[2];
    const float* b1 = (const float*)d_in[3];
    const float* W2 = (const float*)d_in[4];
    const float* b2 = (const float*)d_in[5];

    const int* src = ei;
    const int* dst = ei + N_EDGES;

    // workspace layout
    unsigned short* h1 = (unsigned short*)d_ws;                 // [N][128] bf16 (pre-scaled)
    unsigned short* h2 = h1 + (size_t)N_NODES * HID_C;          // [N][128] bf16 (activations)
    float* dinv  = (float*)(h2 + (size_t)N_NODES * HID_C);      // 50,048 f
    int*   degi  = (int*)(dinv + 50048);                        // 50,048 i (cursor)
    int*   rowptr = degi + 50048;                               // 50,001 i
    int*   csr   = rowptr + 50051;                              // 500,000 i
    int*   bsum  = csr + 500000;                                // 256 i
    unsigned short* h3 = h1;                                    // reuse h1: [N][64] bf16

    // --- CSR build (5 dispatches) ---
    {
        int n4 = (N_NODES + 3) / 4;
        zero_kernel<<<(n4 + 255) / 256, 256, 0, stream>>>((int4*)degi, n4);
    }
    deg_kernel<<<(N_EDGES + 255) / 256, 256, 0, stream>>>(dst, degi);
    scan1_kernel<<<SCAN_NB, 256, 0, stream>>>(degi, rowptr, bsum, dinv);
    scan23_kernel<<<SCAN_NB, 256, 0, stream>>>(rowptr, degi, bsum);
    fill_kernel<<<(N_EDGES + 255) / 256, 256, 0, stream>>>(src, dst, degi, csr);

    const int gemm_grid = (N_NODES + 63) / 64;
    const int agg_grid = N_NODES / 4;  // 12500, 1 node per wave

    // --- layer 1 ---
    mfma_gemm<HID_C, false><<<gemm_grid, 256, 0, stream>>>(x, W1, dinv, h1, N_NODES);
    agg128_kernel<<<agg_grid, 256, 0, stream>>>(rowptr, csr, dinv, (const uint2*)h1, b1,
                                                (uint2*)h2);

    // --- layer 2 ---
    mfma_gemm<OUT_C, true><<<gemm_grid, 256, 0, stream>>>(h2, W2, dinv, h3, N_NODES);
    agg64_kernel<<<agg_grid, 256, 0, stream>>>(rowptr, csr, dinv, (const unsigned int*)h3, b2,
                                               (float2*)d_out);
}